// Round 7
// baseline (66.050 us; speedup 1.0000x reference)
//
#include <hip/hip_runtime.h>
#include <math.h>

#define B_ 2
#define T_ 8
#define N_ 2048
#define F_ 64
#define TI 32                 // i-rows per block: two 16-row A-tiles share B-frags
#define JC 64
#define JCP 72
#define LOG2E 1.44269504088896f
#define PART_STRIDE ((size_t)B_ * T_ * N_ * F_)   // elements per partial buffer

typedef __attribute__((ext_vector_type(8))) short short8;
typedef __attribute__((ext_vector_type(4))) float f32x4;

__device__ __forceinline__ unsigned short f2bf(float x) {
  unsigned u = __float_as_uint(x);
  u += 0x7FFFu + ((u >> 16) & 1u);
  return (unsigned short)(u >> 16);
}

__device__ __forceinline__ unsigned cvt_pk_bf16(float lo, float hi) {
  unsigned r;
  asm("v_cvt_pk_bf16_f32 %0, %1, %2" : "=v"(r) : "v"(lo), "v"(hi));
  return r;
}

__device__ __forceinline__ float bf2f(unsigned short u) {
  return __uint_as_float(((unsigned)u) << 16);
}

// Raw barrier: LDS ordering enforced (lgkmcnt), but register-destined global
// loads stay IN FLIGHT across the barrier (no vmcnt(0) drain like __syncthreads).
#define BARRIER() do {                                      \
    asm volatile("s_waitcnt lgkmcnt(0)" ::: "memory");      \
    __builtin_amdgcn_s_barrier();                           \
    __builtin_amdgcn_sched_barrier(0);                      \
  } while (0)

// ---------------- prep: Wh = h@W (fp32), WhT bf16 [bt][f][j], Wh1/Wh2 (pre-scaled by log2e)
__global__ __launch_bounds__(256) void prep_kernel(
    const float* __restrict__ h, const float* __restrict__ W,
    const float* __restrict__ a, unsigned short* __restrict__ WhT,
    float* __restrict__ Wh1, float* __restrict__ Wh2) {
  __shared__ float Ws[64][64];
  __shared__ float hs[64][64];
  __shared__ float Whs[64][65];
  const int tid = threadIdx.x;
  const int row0 = blockIdx.x * 64;   // row in flattened [B*T*N]
  const int bt = row0 >> 11;
  const int j0 = row0 & 2047;
  for (int i = tid; i < 4096; i += 256) Ws[i >> 6][i & 63] = W[i];
  for (int i = tid; i < 4096; i += 256) hs[i >> 6][i & 63] = h[(size_t)row0 * 64 + i];
  __syncthreads();
  const int f = tid & 63;
  const int rq = tid >> 6;
  float acc[16];
#pragma unroll
  for (int m = 0; m < 16; ++m) acc[m] = 0.f;
#pragma unroll 4
  for (int k = 0; k < 64; ++k) {
    const float wvv = Ws[k][f];
#pragma unroll
    for (int m = 0; m < 16; ++m) acc[m] = fmaf(hs[rq * 16 + m][k], wvv, acc[m]);
  }
#pragma unroll
  for (int m = 0; m < 16; ++m) Whs[rq * 16 + m][f] = acc[m];
  __syncthreads();
  {
    const int r = tid >> 2, q = tid & 3;
    float s1 = 0.f, s2 = 0.f;
#pragma unroll
    for (int k = 0; k < 16; ++k) {
      const float v = Whs[r][q * 16 + k];
      s1 = fmaf(v, a[q * 16 + k], s1);
      s2 = fmaf(v, a[64 + q * 16 + k], s2);
    }
    s1 += __shfl_xor(s1, 1); s1 += __shfl_xor(s1, 2);
    s2 += __shfl_xor(s2, 1); s2 += __shfl_xor(s2, 2);
    if (q == 0) {
      // pre-scale by log2(e): LeakyReLU is positively homogeneous, so
      // exp(LRelu(w1+w2)) == exp2(LRelu(log2e*w1 + log2e*w2))
      Wh1[(size_t)bt * N_ + j0 + r] = s1 * LOG2E;
      Wh2[(size_t)bt * N_ + j0 + r] = s2 * LOG2E;
    }
  }
  {
    const int ff = tid & 63, cp = tid >> 6;
#pragma unroll
    for (int cc = 0; cc < 2; ++cc) {
      const int c = cp * 2 + cc;
      short8 v;
#pragma unroll
      for (int k = 0; k < 8; ++k) v[k] = (short)f2bf(Whs[c * 8 + k][ff]);
      *(short8*)(WhT + ((size_t)bt * 64 + ff) * N_ + j0 + c * 8) = v;
    }
  }
}

// ---------------- main: softmax-over-T attention + MFMA PV -> bf16 partials
// TI=32: two 16-row A-tiles per wave reuse one set of B-fragments.
// njq-way j split; every jq writes its own bf16 partial buffer parts[jq].
__global__ __launch_bounds__(512, 4) void gat_mfma(
    const unsigned short* __restrict__ WhT, const float* __restrict__ Wh1,
    const float* __restrict__ Wh2, const int* __restrict__ adj,
    unsigned short* __restrict__ parts, const int njq) {
  __shared__ unsigned short atts[2][T_][TI][JCP];  // 73728 B
  __shared__ float wh2s[2][T_][JC];                // 4096 B -> 77824 total, 2 blocks/CU
  const int tid = threadIdx.x;
  const int jq = blockIdx.x % njq;
  const int rest = blockIdx.x / njq;
  const int i0 = (rest & 63) * TI;
  const int b = rest >> 6;
  const int jspan = N_ / njq;
  const int jbase = jq * jspan;
  const int nchunk = jspan / JC;

  const int wv = tid >> 6;        // wave id == t
  const int lane = tid & 63;
  const int col = lane & 15;
  const int kg = lane >> 4;

  const int sii = tid >> 4;          // softmax i-row 0..31
  const int sjj = (tid & 15) * 4;    // softmax j-cols sjj..sjj+3
  const int st = tid >> 6, sj = tid & 63;  // wh2 staging assignment

  const unsigned short* wtb = WhT + (size_t)(b * T_ + wv) * F_ * N_;
  const float* wh2b = Wh2 + (size_t)b * T_ * N_;
  const int* adjrow = adj + (size_t)(i0 + sii) * N_ + jbase;

  // Wh1 for this thread's softmax i-row (L2 broadcast loads, once per kernel)
  float w1r[T_];
#pragma unroll
  for (int t = 0; t < T_; ++t) w1r[t] = Wh1[(size_t)(b * T_ + t) * N_ + i0 + sii];

  f32x4 acc[2][4];
#pragma unroll
  for (int it = 0; it < 2; ++it)
#pragma unroll
    for (int nt = 0; nt < 4; ++nt) acc[it][nt] = {0.f, 0.f, 0.f, 0.f};

  // prologue: stage wh2 chunk 0, prefetch adj chunk 0
  wh2s[0][st][sj] = wh2b[(size_t)st * N_ + jbase + sj];
  int4 ad = *(const int4*)(adjrow + sjj);
  BARRIER();

  for (int c = 0; c < nchunk; ++c) {
    const int j0 = jbase + c * JC;
    const int buf = c & 1;
    // --- issue B-fragment global loads early (shared by both A-tiles);
    //     with the raw barrier these stay in flight until the MFMA's vmcnt
    short8 breg[4][2];
#pragma unroll
    for (int nt = 0; nt < 4; ++nt)
#pragma unroll
      for (int ks = 0; ks < 2; ++ks)
        breg[nt][ks] = *(const short8*)(wtb + (size_t)(nt * 16 + col) * N_ +
                                        j0 + ks * 32 + kg * 8);
    // --- stage next chunk's Wh2 (safe: buf^1 readers all passed barrier(c-1))
    if (c + 1 < nchunk)
      wh2s[buf ^ 1][st][sj] = wh2b[(size_t)st * N_ + j0 + JC + sj];
    // --- prefetch next chunk's adj
    int4 adn = ad;
    if (c + 1 < nchunk) adn = *(const int4*)(adjrow + (c + 1) * JC + sjj);

    // --- softmax over T: row sii, cols sjj..sjj+3 (2 register-light passes)
#pragma unroll
    for (int g = 0; g < 2; ++g) {
      const int c0 = sjj + 2 * g;
      const int a0i = g == 0 ? ad.x : ad.z;
      const int a1i = g == 0 ? ad.y : ad.w;
      float e0[T_], e1[T_];
      float s0 = 0.f, s1 = 0.f;
#pragma unroll
      for (int t = 0; t < T_; ++t) {
        const float2 w2 = *(const float2*)(&wh2s[buf][t][c0]);
        float x0 = w1r[t] + w2.x;
        float x1 = w1r[t] + w2.y;
        x0 = fmaxf(x0, 0.2f * x0);   // LeakyReLU (alpha<1, scale-commuting)
        x1 = fmaxf(x1, 0.2f * x1);
        e0[t] = __builtin_amdgcn_exp2f(x0);
        e1[t] = __builtin_amdgcn_exp2f(x1);
        s0 += e0[t];
        s1 += e1[t];
      }
      // adj==0 -> all-NEG_INF column -> softmax over t uniform 1/8
      const float r0 = a0i > 0 ? __builtin_amdgcn_rcpf(s0) : 0.f;
      const float r1 = a1i > 0 ? __builtin_amdgcn_rcpf(s1) : 0.f;
      const float d0 = a0i > 0 ? 0.f : 0.125f;
      const float d1 = a1i > 0 ? 0.f : 0.125f;
#pragma unroll
      for (int t = 0; t < T_; ++t) {
        const float av0 = fmaf(e0[t], r0, d0);
        const float av1 = fmaf(e1[t], r1, d1);
        *(unsigned*)&atts[buf][t][sii][c0] = cvt_pk_bf16(av0, av1);
      }
    }
    ad = adn;
    BARRIER();
    // --- MFMA: two A-tiles (rows 0-15, 16-31) x 4 f-tiles, reusing breg
    __builtin_amdgcn_s_setprio(1);
#pragma unroll
    for (int it = 0; it < 2; ++it) {
      const unsigned short* ab = &atts[buf][wv][it * 16 + col][kg * 8];
      const short8 a0 = *(const short8*)ab;
      const short8 a1 = *(const short8*)(ab + 32);
#pragma unroll
      for (int nt = 0; nt < 4; ++nt) {
        acc[it][nt] = __builtin_amdgcn_mfma_f32_16x16x32_bf16(a0, breg[nt][0], acc[it][nt], 0, 0, 0);
        acc[it][nt] = __builtin_amdgcn_mfma_f32_16x16x32_bf16(a1, breg[nt][1], acc[it][nt], 0, 0, 0);
      }
    }
    __builtin_amdgcn_s_setprio(0);
  }

  // ---- epilogue: bf16 partial store (1 cvt inst/elem). C/D: col=lane&15,
  // row=(lane>>4)*4+reg. Each jq owns a disjoint buffer -> no false sharing.
  unsigned short* ob = parts + (size_t)jq * PART_STRIDE +
                       ((size_t)(b * T_ + wv) * N_ + i0) * F_;
#pragma unroll
  for (int it = 0; it < 2; ++it) {
#pragma unroll
    for (int nt = 0; nt < 4; ++nt) {
#pragma unroll
      for (int r = 0; r < 4; ++r) {
        const int row = it * 16 + kg * 4 + r;
        const float x = acc[it][nt][r];
        ob[(size_t)row * F_ + nt * 16 + col] = (unsigned short)cvt_pk_bf16(x, x);
      }
    }
  }
}

// ---------------- combine njq bf16 partials + ELU -> fp32 out
__global__ __launch_bounds__(256) void combine_elu(
    float* __restrict__ out, const unsigned short* __restrict__ parts,
    const int njq) {
  const size_t i = ((size_t)blockIdx.x * 256 + threadIdx.x) * 8;
  float s[8] = {0.f, 0.f, 0.f, 0.f, 0.f, 0.f, 0.f, 0.f};
  for (int p = 0; p < njq; ++p) {
    const short8 v = *(const short8*)(parts + (size_t)p * PART_STRIDE + i);
#pragma unroll
    for (int k = 0; k < 8; ++k) s[k] += bf2f((unsigned short)v[k]);
  }
  f32x4 lo, hi;
#pragma unroll
  for (int k = 0; k < 4; ++k) {
    lo[k] = s[k] > 0.f ? s[k] : expm1f(s[k]);
    hi[k] = s[4 + k] > 0.f ? s[4 + k] : expm1f(s[4 + k]);
  }
  *(f32x4*)(out + i) = lo;
  *(f32x4*)(out + i + 4) = hi;
}

extern "C" void kernel_launch(void* const* d_in, const int* in_sizes, int n_in,
                              void* d_out, int out_size, void* d_ws, size_t ws_size,
                              hipStream_t stream) {
  const float* h   = (const float*)d_in[0];
  const float* W   = (const float*)d_in[1];
  const float* a   = (const float*)d_in[2];
  const int*   adj = (const int*)d_in[3];
  float* out = (float*)d_out;

  const size_t whtBytes = (size_t)B_ * T_ * F_ * N_ * 2;    // 4MB
  const size_t vBytes   = (size_t)B_ * T_ * N_ * 4;         // 128KB
  const size_t partB    = PART_STRIDE * 2;                  // 4.2MB each (bf16)

  unsigned short* WhT = (unsigned short*)d_ws;
  float* Wh1 = (float*)((char*)d_ws + whtBytes);
  float* Wh2 = Wh1 + (size_t)B_ * T_ * N_;
  unsigned short* parts = (unsigned short*)(Wh2 + (size_t)B_ * T_ * N_);

  const size_t fixed = whtBytes + 2 * vBytes;
  const int njq = (ws_size >= fixed + 8 * partB) ? 8
                : (ws_size >= fixed + 2 * partB) ? 2 : 1;

  hipLaunchKernelGGL(prep_kernel, dim3(B_ * T_ * N_ / 64), dim3(256), 0, stream,
                     h, W, a, WhT, Wh1, Wh2);
  hipLaunchKernelGGL(gat_mfma, dim3(B_ * (N_ / TI) * njq), dim3(512), 0, stream,
                     WhT, Wh1, Wh2, adj, parts, njq);
  hipLaunchKernelGGL(combine_elu, dim3((unsigned)(PART_STRIDE / (256 * 8))), dim3(256),
                     0, stream, out, parts, njq);
}

// Round 8
// 65.203 us; speedup vs baseline: 1.0130x; 1.0130x over previous
//
#include <hip/hip_runtime.h>
#include <math.h>

#define B_ 2
#define T_ 8
#define N_ 2048
#define F_ 64
#define TI 32                 // i-rows per block: two 16-row A-tiles share B-frags
#define JC 64
#define JCP 72
#define LOG2E 1.44269504088896f
#define PART_STRIDE ((size_t)B_ * T_ * N_ * F_)   // elements per partial buffer

typedef __attribute__((ext_vector_type(8))) short short8;
typedef __attribute__((ext_vector_type(4))) float f32x4;

__device__ __forceinline__ unsigned short f2bf(float x) {
  unsigned u = __float_as_uint(x);
  u += 0x7FFFu + ((u >> 16) & 1u);
  return (unsigned short)(u >> 16);
}

__device__ __forceinline__ unsigned cvt_pk_bf16(float lo, float hi) {
  unsigned r;
  asm("v_cvt_pk_bf16_f32 %0, %1, %2" : "=v"(r) : "v"(lo), "v"(hi));
  return r;
}

__device__ __forceinline__ float bf2f(unsigned short u) {
  return __uint_as_float(((unsigned)u) << 16);
}

// Raw barrier: LDS ordering enforced (lgkmcnt), but register-destined global
// loads stay IN FLIGHT across the barrier (no vmcnt(0) drain like __syncthreads).
#define BARRIER() do {                                      \
    asm volatile("s_waitcnt lgkmcnt(0)" ::: "memory");      \
    __builtin_amdgcn_s_barrier();                           \
    __builtin_amdgcn_sched_barrier(0);                      \
  } while (0)

// ---------------- prep: Wh = h@W (fp32), WhT bf16 [bt][f][j], Wh1/Wh2 (pre-scaled by log2e)
__global__ __launch_bounds__(256) void prep_kernel(
    const float* __restrict__ h, const float* __restrict__ W,
    const float* __restrict__ a, unsigned short* __restrict__ WhT,
    float* __restrict__ Wh1, float* __restrict__ Wh2) {
  __shared__ float Ws[64][64];
  __shared__ float hs[64][64];
  __shared__ float Whs[64][65];
  const int tid = threadIdx.x;
  const int row0 = blockIdx.x * 64;   // row in flattened [B*T*N]
  const int bt = row0 >> 11;
  const int j0 = row0 & 2047;
  for (int i = tid; i < 4096; i += 256) Ws[i >> 6][i & 63] = W[i];
  for (int i = tid; i < 4096; i += 256) hs[i >> 6][i & 63] = h[(size_t)row0 * 64 + i];
  __syncthreads();
  const int f = tid & 63;
  const int rq = tid >> 6;
  float acc[16];
#pragma unroll
  for (int m = 0; m < 16; ++m) acc[m] = 0.f;
#pragma unroll 4
  for (int k = 0; k < 64; ++k) {
    const float wvv = Ws[k][f];
#pragma unroll
    for (int m = 0; m < 16; ++m) acc[m] = fmaf(hs[rq * 16 + m][k], wvv, acc[m]);
  }
#pragma unroll
  for (int m = 0; m < 16; ++m) Whs[rq * 16 + m][f] = acc[m];
  __syncthreads();
  {
    const int r = tid >> 2, q = tid & 3;
    float s1 = 0.f, s2 = 0.f;
#pragma unroll
    for (int k = 0; k < 16; ++k) {
      const float v = Whs[r][q * 16 + k];
      s1 = fmaf(v, a[q * 16 + k], s1);
      s2 = fmaf(v, a[64 + q * 16 + k], s2);
    }
    s1 += __shfl_xor(s1, 1); s1 += __shfl_xor(s1, 2);
    s2 += __shfl_xor(s2, 1); s2 += __shfl_xor(s2, 2);
    if (q == 0) {
      // pre-scale by log2(e): LeakyReLU is positively homogeneous, so
      // exp(LRelu(w1+w2)) == exp2(LRelu(log2e*w1 + log2e*w2))
      Wh1[(size_t)bt * N_ + j0 + r] = s1 * LOG2E;
      Wh2[(size_t)bt * N_ + j0 + r] = s2 * LOG2E;
    }
  }
  {
    const int ff = tid & 63, cp = tid >> 6;
#pragma unroll
    for (int cc = 0; cc < 2; ++cc) {
      const int c = cp * 2 + cc;
      short8 v;
#pragma unroll
      for (int k = 0; k < 8; ++k) v[k] = (short)f2bf(Whs[c * 8 + k][ff]);
      *(short8*)(WhT + ((size_t)bt * 64 + ff) * N_ + j0 + c * 8) = v;
    }
  }
}

// ---------------- main: softmax-over-T attention + MFMA PV -> bf16 partials
// TI=32: two 16-row A-tiles per wave reuse one set of B-fragments.
// njq-way j split; every jq writes its own bf16 partial buffer parts[jq].
__global__ __launch_bounds__(512, 4) void gat_mfma(
    const unsigned short* __restrict__ WhT, const float* __restrict__ Wh1,
    const float* __restrict__ Wh2, const int* __restrict__ adj,
    unsigned short* __restrict__ parts, const int njq) {
  __shared__ unsigned short atts[2][T_][TI][JCP];  // 73728 B
  __shared__ float wh2s[2][T_][JC];                // 4096 B -> 77824 total, 2 blocks/CU
  const int tid = threadIdx.x;
  const int jq = blockIdx.x % njq;
  const int rest = blockIdx.x / njq;
  const int i0 = (rest & 63) * TI;
  const int b = rest >> 6;
  const int jspan = N_ / njq;
  const int jbase = jq * jspan;
  const int nchunk = jspan / JC;

  const int wv = tid >> 6;        // wave id == t
  const int lane = tid & 63;
  const int col = lane & 15;
  const int kg = lane >> 4;

  const int sii = tid >> 4;          // softmax i-row 0..31
  const int sjj = (tid & 15) * 4;    // softmax j-cols sjj..sjj+3
  const int st = tid >> 6, sj = tid & 63;  // wh2 staging assignment

  const unsigned short* wtb = WhT + (size_t)(b * T_ + wv) * F_ * N_;
  const float* wh2b = Wh2 + (size_t)b * T_ * N_;
  const int* adjrow = adj + (size_t)(i0 + sii) * N_ + jbase;

  // Wh1 for this thread's softmax i-row (L2 broadcast loads, once per kernel)
  float w1r[T_];
#pragma unroll
  for (int t = 0; t < T_; ++t) w1r[t] = Wh1[(size_t)(b * T_ + t) * N_ + i0 + sii];

  f32x4 acc[2][4];
#pragma unroll
  for (int it = 0; it < 2; ++it)
#pragma unroll
    for (int nt = 0; nt < 4; ++nt) acc[it][nt] = {0.f, 0.f, 0.f, 0.f};

  // prologue: stage wh2 chunk 0, prefetch adj chunk 0
  wh2s[0][st][sj] = wh2b[(size_t)st * N_ + jbase + sj];
  int4 ad = *(const int4*)(adjrow + sjj);
  BARRIER();

  for (int c = 0; c < nchunk; ++c) {
    const int j0 = jbase + c * JC;
    const int buf = c & 1;
    // --- issue B-fragment global loads early (shared by both A-tiles);
    //     they stay in flight until the MFMA's own vmcnt wait
    short8 breg[4][2];
#pragma unroll
    for (int nt = 0; nt < 4; ++nt)
#pragma unroll
      for (int ks = 0; ks < 2; ++ks)
        breg[nt][ks] = *(const short8*)(wtb + (size_t)(nt * 16 + col) * N_ +
                                        j0 + ks * 32 + kg * 8);
    // --- stage next chunk's Wh2 (safe: buf^1 readers all passed barrier(c-1))
    if (c + 1 < nchunk)
      wh2s[buf ^ 1][st][sj] = wh2b[(size_t)st * N_ + j0 + JC + sj];
    // --- prefetch next chunk's adj
    int4 adn = ad;
    if (c + 1 < nchunk) adn = *(const int4*)(adjrow + (c + 1) * JC + sjj);

    // --- softmax over T: row sii, 4 cols sjj..sjj+3, batched:
    //     1 ds_read_b128 per t, 1 ds_write_b64 per t (LDS ops 37->21/thread)
    {
      float e[T_][4];
      f32x4 s = {0.f, 0.f, 0.f, 0.f};
#pragma unroll
      for (int t = 0; t < T_; ++t) {
        const f32x4 q = *(const f32x4*)(&wh2s[buf][t][sjj]);
#pragma unroll
        for (int cc = 0; cc < 4; ++cc) {
          float x = w1r[t] + q[cc];
          x = fmaxf(x, 0.2f * x);   // LeakyReLU (alpha<1, scale-commuting)
          e[t][cc] = __builtin_amdgcn_exp2f(x);
          s[cc] += e[t][cc];
        }
      }
      // adj==0 -> all-NEG_INF column -> softmax over t uniform 1/8
      const int adc[4] = {ad.x, ad.y, ad.z, ad.w};
      float rr[4], dd[4];
#pragma unroll
      for (int cc = 0; cc < 4; ++cc) {
        rr[cc] = adc[cc] > 0 ? __builtin_amdgcn_rcpf(s[cc]) : 0.f;
        dd[cc] = adc[cc] > 0 ? 0.f : 0.125f;
      }
#pragma unroll
      for (int t = 0; t < T_; ++t) {
        const float a0 = fmaf(e[t][0], rr[0], dd[0]);
        const float a1 = fmaf(e[t][1], rr[1], dd[1]);
        const float a2 = fmaf(e[t][2], rr[2], dd[2]);
        const float a3 = fmaf(e[t][3], rr[3], dd[3]);
        uint2 w;
        w.x = cvt_pk_bf16(a0, a1);
        w.y = cvt_pk_bf16(a2, a3);
        *(uint2*)&atts[buf][t][sii][sjj] = w;
      }
    }
    ad = adn;
    BARRIER();
    // --- MFMA: two A-tiles (rows 0-15, 16-31) x 4 f-tiles, reusing breg
    __builtin_amdgcn_s_setprio(1);
#pragma unroll
    for (int it = 0; it < 2; ++it) {
      const unsigned short* ab = &atts[buf][wv][it * 16 + col][kg * 8];
      const short8 a0 = *(const short8*)ab;
      const short8 a1 = *(const short8*)(ab + 32);
#pragma unroll
      for (int nt = 0; nt < 4; ++nt) {
        acc[it][nt] = __builtin_amdgcn_mfma_f32_16x16x32_bf16(a0, breg[nt][0], acc[it][nt], 0, 0, 0);
        acc[it][nt] = __builtin_amdgcn_mfma_f32_16x16x32_bf16(a1, breg[nt][1], acc[it][nt], 0, 0, 0);
      }
    }
    __builtin_amdgcn_s_setprio(0);
  }

  // ---- epilogue: bf16 partial store (1 cvt inst/elem). C/D: col=lane&15,
  // row=(lane>>4)*4+reg. Each jq owns a disjoint buffer -> no false sharing.
  unsigned short* ob = parts + (size_t)jq * PART_STRIDE +
                       ((size_t)(b * T_ + wv) * N_ + i0) * F_;
#pragma unroll
  for (int it = 0; it < 2; ++it) {
#pragma unroll
    for (int nt = 0; nt < 4; ++nt) {
#pragma unroll
      for (int r = 0; r < 4; ++r) {
        const int row = it * 16 + kg * 4 + r;
        const float x = acc[it][nt][r];
        ob[(size_t)row * F_ + nt * 16 + col] = (unsigned short)cvt_pk_bf16(x, x);
      }
    }
  }
}

// ---------------- combine njq bf16 partials + ELU -> fp32 out
__global__ __launch_bounds__(256) void combine_elu(
    float* __restrict__ out, const unsigned short* __restrict__ parts,
    const int njq) {
  const size_t i = ((size_t)blockIdx.x * 256 + threadIdx.x) * 8;
  float s[8] = {0.f, 0.f, 0.f, 0.f, 0.f, 0.f, 0.f, 0.f};
  for (int p = 0; p < njq; ++p) {
    const short8 v = *(const short8*)(parts + (size_t)p * PART_STRIDE + i);
#pragma unroll
    for (int k = 0; k < 8; ++k) s[k] += bf2f((unsigned short)v[k]);
  }
  f32x4 lo, hi;
#pragma unroll
  for (int k = 0; k < 4; ++k) {
    lo[k] = s[k] > 0.f ? s[k] : expm1f(s[k]);
    hi[k] = s[4 + k] > 0.f ? s[4 + k] : expm1f(s[4 + k]);
  }
  *(f32x4*)(out + i) = lo;
  *(f32x4*)(out + i + 4) = hi;
}

extern "C" void kernel_launch(void* const* d_in, const int* in_sizes, int n_in,
                              void* d_out, int out_size, void* d_ws, size_t ws_size,
                              hipStream_t stream) {
  const float* h   = (const float*)d_in[0];
  const float* W   = (const float*)d_in[1];
  const float* a   = (const float*)d_in[2];
  const int*   adj = (const int*)d_in[3];
  float* out = (float*)d_out;

  const size_t whtBytes = (size_t)B_ * T_ * F_ * N_ * 2;    // 4MB
  const size_t vBytes   = (size_t)B_ * T_ * N_ * 4;         // 128KB
  const size_t partB    = PART_STRIDE * 2;                  // 4.2MB each (bf16)

  unsigned short* WhT = (unsigned short*)d_ws;
  float* Wh1 = (float*)((char*)d_ws + whtBytes);
  float* Wh2 = Wh1 + (size_t)B_ * T_ * N_;
  unsigned short* parts = (unsigned short*)(Wh2 + (size_t)B_ * T_ * N_);

  const size_t fixed = whtBytes + 2 * vBytes;
  const int njq = (ws_size >= fixed + 4 * partB) ? 4
                : (ws_size >= fixed + 2 * partB) ? 2 : 1;

  hipLaunchKernelGGL(prep_kernel, dim3(B_ * T_ * N_ / 64), dim3(256), 0, stream,
                     h, W, a, WhT, Wh1, Wh2);
  hipLaunchKernelGGL(gat_mfma, dim3(B_ * (N_ / TI) * njq), dim3(512), 0, stream,
                     WhT, Wh1, Wh2, adj, parts, njq);
  hipLaunchKernelGGL(combine_elu, dim3((unsigned)(PART_STRIDE / (256 * 8))), dim3(256),
                     0, stream, out, parts, njq);
}

// Round 9
// 61.957 us; speedup vs baseline: 1.0661x; 1.0524x over previous
//
#include <hip/hip_runtime.h>
#include <math.h>

#define B_ 2
#define T_ 8
#define N_ 2048
#define F_ 64
#define TI 32                 // i-rows per block: two 16-row A-tiles share B-frags
#define JC 64
#define JCP 72
#define LOG2E 1.44269504088896f
#define PART_STRIDE ((size_t)B_ * T_ * N_ * F_)   // elements per partial buffer

typedef __attribute__((ext_vector_type(8))) short short8;
typedef __attribute__((ext_vector_type(4))) float f32x4;

__device__ __forceinline__ unsigned short f2bf(float x) {
  unsigned u = __float_as_uint(x);
  u += 0x7FFFu + ((u >> 16) & 1u);
  return (unsigned short)(u >> 16);
}

__device__ __forceinline__ unsigned cvt_pk_bf16(float lo, float hi) {
  unsigned r;
  asm("v_cvt_pk_bf16_f32 %0, %1, %2" : "=v"(r) : "v"(lo), "v"(hi));
  return r;
}

__device__ __forceinline__ float bf2f(unsigned short u) {
  return __uint_as_float(((unsigned)u) << 16);
}

// ---------------- prep: Wh = h@W (fp32), WhT bf16 [bt][f][j], Wh1/Wh2 (pre-scaled by log2e)
__global__ __launch_bounds__(256) void prep_kernel(
    const float* __restrict__ h, const float* __restrict__ W,
    const float* __restrict__ a, unsigned short* __restrict__ WhT,
    float* __restrict__ Wh1, float* __restrict__ Wh2) {
  __shared__ float Ws[64][64];
  __shared__ float hs[64][64];
  __shared__ float Whs[64][65];
  const int tid = threadIdx.x;
  const int row0 = blockIdx.x * 64;   // row in flattened [B*T*N]
  const int bt = row0 >> 11;
  const int j0 = row0 & 2047;
  for (int i = tid; i < 4096; i += 256) Ws[i >> 6][i & 63] = W[i];
  for (int i = tid; i < 4096; i += 256) hs[i >> 6][i & 63] = h[(size_t)row0 * 64 + i];
  __syncthreads();
  const int f = tid & 63;
  const int rq = tid >> 6;
  float acc[16];
#pragma unroll
  for (int m = 0; m < 16; ++m) acc[m] = 0.f;
#pragma unroll 4
  for (int k = 0; k < 64; ++k) {
    const float wvv = Ws[k][f];
#pragma unroll
    for (int m = 0; m < 16; ++m) acc[m] = fmaf(hs[rq * 16 + m][k], wvv, acc[m]);
  }
#pragma unroll
  for (int m = 0; m < 16; ++m) Whs[rq * 16 + m][f] = acc[m];
  __syncthreads();
  {
    const int r = tid >> 2, q = tid & 3;
    float s1 = 0.f, s2 = 0.f;
#pragma unroll
    for (int k = 0; k < 16; ++k) {
      const float v = Whs[r][q * 16 + k];
      s1 = fmaf(v, a[q * 16 + k], s1);
      s2 = fmaf(v, a[64 + q * 16 + k], s2);
    }
    s1 += __shfl_xor(s1, 1); s1 += __shfl_xor(s1, 2);
    s2 += __shfl_xor(s2, 1); s2 += __shfl_xor(s2, 2);
    if (q == 0) {
      // pre-scale by log2(e): LeakyReLU is positively homogeneous, so
      // exp(LRelu(w1+w2)) == exp2(LRelu(log2e*w1 + log2e*w2))
      Wh1[(size_t)bt * N_ + j0 + r] = s1 * LOG2E;
      Wh2[(size_t)bt * N_ + j0 + r] = s2 * LOG2E;
    }
  }
  {
    const int ff = tid & 63, cp = tid >> 6;
#pragma unroll
    for (int cc = 0; cc < 2; ++cc) {
      const int c = cp * 2 + cc;
      short8 v;
#pragma unroll
      for (int k = 0; k < 8; ++k) v[k] = (short)f2bf(Whs[c * 8 + k][ff]);
      *(short8*)(WhT + ((size_t)bt * 64 + ff) * N_ + j0 + c * 8) = v;
    }
  }
}

// ---------------- main: softmax-over-T attention + MFMA PV -> bf16 partials
// TI=32: two 16-row A-tiles per wave reuse one set of B-fragments.
// njq-way j split; every jq writes its own bf16 partial buffer parts[jq].
// XCD swizzle (njq==4): logical L = ((b*4+jq)*64 + itile); physical bx ->
// L = (bx&7)*64 + (bx>>3), so each XCD's round-robin share is one (b,jq)
// group of 64 itile-blocks sharing a 512KB WhT slice + 4MB adj column-span.
__global__ __launch_bounds__(512, 4) void gat_mfma(
    const unsigned short* __restrict__ WhT, const float* __restrict__ Wh1,
    const float* __restrict__ Wh2, const int* __restrict__ adj,
    unsigned short* __restrict__ parts, const int njq) {
  __shared__ unsigned short atts[2][T_][TI][JCP];  // 73728 B
  __shared__ float wh2s[2][T_][JC];                // 4096 B -> 77824 total, 2 blocks/CU
  const int tid = threadIdx.x;
  int L = blockIdx.x;
  if (njq == 4) L = (blockIdx.x & 7) * 64 + (blockIdx.x >> 3);  // bijective, 512 blocks
  const int itile = L & 63;
  const int group = L >> 6;
  const int jq = group & (njq - 1);
  const int b = group / njq;
  const int i0 = itile * TI;
  const int jspan = N_ / njq;
  const int jbase = jq * jspan;
  const int nchunk = jspan / JC;

  const int wv = tid >> 6;        // wave id == t
  const int lane = tid & 63;
  const int col = lane & 15;
  const int kg = lane >> 4;

  const int sii = tid >> 4;          // softmax i-row 0..31
  const int sjj = (tid & 15) * 4;    // softmax j-cols sjj..sjj+3
  const int st = tid >> 6, sj = tid & 63;  // wh2 staging assignment

  const unsigned short* wtb = WhT + (size_t)(b * T_ + wv) * F_ * N_;
  const float* wh2b = Wh2 + (size_t)b * T_ * N_;
  const int* adjrow = adj + (size_t)(i0 + sii) * N_ + jbase;

  // Wh1 for this thread's softmax i-row (L2 broadcast loads, once per kernel)
  float w1r[T_];
#pragma unroll
  for (int t = 0; t < T_; ++t) w1r[t] = Wh1[(size_t)(b * T_ + t) * N_ + i0 + sii];

  f32x4 acc[2][4];
#pragma unroll
  for (int it = 0; it < 2; ++it)
#pragma unroll
    for (int nt = 0; nt < 4; ++nt) acc[it][nt] = {0.f, 0.f, 0.f, 0.f};

  // prologue: stage wh2 chunk 0, prefetch adj chunk 0
  wh2s[0][st][sj] = wh2b[(size_t)st * N_ + jbase + sj];
  int4 ad = *(const int4*)(adjrow + sjj);
  __syncthreads();

  for (int c = 0; c < nchunk; ++c) {
    const int j0 = jbase + c * JC;
    const int buf = c & 1;
    // --- issue B-fragment global loads early (shared by both A-tiles)
    short8 breg[4][2];
#pragma unroll
    for (int nt = 0; nt < 4; ++nt)
#pragma unroll
      for (int ks = 0; ks < 2; ++ks)
        breg[nt][ks] = *(const short8*)(wtb + (size_t)(nt * 16 + col) * N_ +
                                        j0 + ks * 32 + kg * 8);
    // --- stage next chunk's Wh2 (safe: buf^1 readers all passed barrier(c-1))
    if (c + 1 < nchunk)
      wh2s[buf ^ 1][st][sj] = wh2b[(size_t)st * N_ + j0 + JC + sj];
    // --- prefetch next chunk's adj
    int4 adn = ad;
    if (c + 1 < nchunk) adn = *(const int4*)(adjrow + (c + 1) * JC + sjj);

    // --- softmax over T: row sii, 4 cols sjj..sjj+3, batched:
    //     1 ds_read_b128 per t, 1 ds_write_b64 per t (conflict-free layout)
    {
      float e[T_][4];
      f32x4 s = {0.f, 0.f, 0.f, 0.f};
#pragma unroll
      for (int t = 0; t < T_; ++t) {
        const f32x4 q = *(const f32x4*)(&wh2s[buf][t][sjj]);
#pragma unroll
        for (int cc = 0; cc < 4; ++cc) {
          float x = w1r[t] + q[cc];
          x = fmaxf(x, 0.2f * x);   // LeakyReLU (alpha<1, scale-commuting)
          e[t][cc] = __builtin_amdgcn_exp2f(x);
          s[cc] += e[t][cc];
        }
      }
      // adj==0 -> all-NEG_INF column -> softmax over t uniform 1/8
      const int adc[4] = {ad.x, ad.y, ad.z, ad.w};
      float rr[4], dd[4];
#pragma unroll
      for (int cc = 0; cc < 4; ++cc) {
        rr[cc] = adc[cc] > 0 ? __builtin_amdgcn_rcpf(s[cc]) : 0.f;
        dd[cc] = adc[cc] > 0 ? 0.f : 0.125f;
      }
#pragma unroll
      for (int t = 0; t < T_; ++t) {
        const float a0 = fmaf(e[t][0], rr[0], dd[0]);
        const float a1 = fmaf(e[t][1], rr[1], dd[1]);
        const float a2 = fmaf(e[t][2], rr[2], dd[2]);
        const float a3 = fmaf(e[t][3], rr[3], dd[3]);
        uint2 w;
        w.x = cvt_pk_bf16(a0, a1);
        w.y = cvt_pk_bf16(a2, a3);
        *(uint2*)&atts[buf][t][sii][sjj] = w;
      }
    }
    ad = adn;
    __syncthreads();
    // --- MFMA: two A-tiles (rows 0-15, 16-31) x 4 f-tiles, reusing breg.
    // (MFMA(c) overlaps softmax(c+1) across the back-edge: no barrier between.)
#pragma unroll
    for (int it = 0; it < 2; ++it) {
      const unsigned short* ab = &atts[buf][wv][it * 16 + col][kg * 8];
      const short8 a0 = *(const short8*)ab;
      const short8 a1 = *(const short8*)(ab + 32);
#pragma unroll
      for (int nt = 0; nt < 4; ++nt) {
        acc[it][nt] = __builtin_amdgcn_mfma_f32_16x16x32_bf16(a0, breg[nt][0], acc[it][nt], 0, 0, 0);
        acc[it][nt] = __builtin_amdgcn_mfma_f32_16x16x32_bf16(a1, breg[nt][1], acc[it][nt], 0, 0, 0);
      }
    }
  }

  // ---- epilogue: bf16 partial store (1 cvt inst/elem). C/D: col=lane&15,
  // row=(lane>>4)*4+reg. Each jq owns a disjoint buffer -> no false sharing.
  unsigned short* ob = parts + (size_t)jq * PART_STRIDE +
                       ((size_t)(b * T_ + wv) * N_ + i0) * F_;
#pragma unroll
  for (int it = 0; it < 2; ++it) {
#pragma unroll
    for (int nt = 0; nt < 4; ++nt) {
#pragma unroll
      for (int r = 0; r < 4; ++r) {
        const int row = it * 16 + kg * 4 + r;
        const float x = acc[it][nt][r];
        ob[(size_t)row * F_ + nt * 16 + col] = (unsigned short)cvt_pk_bf16(x, x);
      }
    }
  }
}

// ---------------- combine njq bf16 partials + ELU -> fp32 out
__global__ __launch_bounds__(256) void combine_elu(
    float* __restrict__ out, const unsigned short* __restrict__ parts,
    const int njq) {
  const size_t i = ((size_t)blockIdx.x * 256 + threadIdx.x) * 8;
  float s[8] = {0.f, 0.f, 0.f, 0.f, 0.f, 0.f, 0.f, 0.f};
  for (int p = 0; p < njq; ++p) {
    const short8 v = *(const short8*)(parts + (size_t)p * PART_STRIDE + i);
#pragma unroll
    for (int k = 0; k < 8; ++k) s[k] += bf2f((unsigned short)v[k]);
  }
  f32x4 lo, hi;
#pragma unroll
  for (int k = 0; k < 4; ++k) {
    lo[k] = s[k] > 0.f ? s[k] : expm1f(s[k]);
    hi[k] = s[4 + k] > 0.f ? s[4 + k] : expm1f(s[4 + k]);
  }
  *(f32x4*)(out + i) = lo;
  *(f32x4*)(out + i + 4) = hi;
}

extern "C" void kernel_launch(void* const* d_in, const int* in_sizes, int n_in,
                              void* d_out, int out_size, void* d_ws, size_t ws_size,
                              hipStream_t stream) {
  const float* h   = (const float*)d_in[0];
  const float* W   = (const float*)d_in[1];
  const float* a   = (const float*)d_in[2];
  const int*   adj = (const int*)d_in[3];
  float* out = (float*)d_out;

  const size_t whtBytes = (size_t)B_ * T_ * F_ * N_ * 2;    // 4MB
  const size_t vBytes   = (size_t)B_ * T_ * N_ * 4;         // 128KB
  const size_t partB    = PART_STRIDE * 2;                  // 4.2MB each (bf16)

  unsigned short* WhT = (unsigned short*)d_ws;
  float* Wh1 = (float*)((char*)d_ws + whtBytes);
  float* Wh2 = Wh1 + (size_t)B_ * T_ * N_;
  unsigned short* parts = (unsigned short*)(Wh2 + (size_t)B_ * T_ * N_);

  const size_t fixed = whtBytes + 2 * vBytes;
  const int njq = (ws_size >= fixed + 4 * partB) ? 4
                : (ws_size >= fixed + 2 * partB) ? 2 : 1;

  hipLaunchKernelGGL(prep_kernel, dim3(B_ * T_ * N_ / 64), dim3(256), 0, stream,
                     h, W, a, WhT, Wh1, Wh2);
  hipLaunchKernelGGL(gat_mfma, dim3(B_ * (N_ / TI) * njq), dim3(512), 0, stream,
                     WhT, Wh1, Wh2, adj, parts, njq);
  hipLaunchKernelGGL(combine_elu, dim3((unsigned)(PART_STRIDE / (256 * 8))), dim3(256),
                     0, stream, out, parts, njq);
}